// Round 5
// baseline (74.314 us; speedup 1.0000x reference)
//
#include <hip/hip_runtime.h>
#include <math.h>

// XYSearcher, sliding-window banded-GEMM, 32x32x16 MFMA edition.
//   ||q_a - p_b||^2 = ||q_a||^2 + ||p_b||^2 - 2 q_a.p_b
// Integer steps: step k pairs rows at delta = a-b = +(k+1) [pos] or -(k+1)
// [neg]; one wrapped corner pair per step (corner_kernel, exact fp32).
// Dots in bf16 MFMA, norms exact fp32 (absmax 0 verified rounds 3-4).
// Block: 512 thr (8 waves). A-subtile = 32 Q rows; B-window = 5 P tiles of 32
// rows (delta coverage [-95,95] >= [-61,60]). 6-slot P ring + Q dbuf in LDS,
// row stride 560B -> 16B-slot = 3*row mod 32: conflict-free b128 frag reads.
// Per-thread delta is T-invariant -> 16 step slots precomputed, norm-sums in
// registers; contended LDS atomics + runtime division once per block.

typedef __attribute__((ext_vector_type(8))) __bf16 bf16x8;
typedef __attribute__((ext_vector_type(16))) float f32x16;

#define LDSH 280     // shorts per LDS row (560 B = 35 x 16B slots)
#define RING 6       // P ring: 5-tile window + 1 incoming
#define MAXS 128
#define NREP 32

__global__ __launch_bounds__(512, 1)
void band_kernel(const float* __restrict__ Q, const float* __restrict__ P,
                 double* __restrict__ ws,
                 const int* __restrict__ msp, const int* __restrict__ ssp,
                 int N, int TS, int nsb) {
  __shared__ __align__(16) unsigned short Bsh[RING * 32 * LDSH];  // 105 KB
  __shared__ __align__(16) unsigned short Qsh[2 * 32 * LDSH];     // 35 KB
  __shared__ float NpS[RING * 32];
  __shared__ float NqS[2 * 32];
  __shared__ float sums[MAXS];

  const int t = threadIdx.x;
  const int ms = msp[0], ss = ssp[0];
  const int S1 = (ms + ss - 1) / ss;
  const int S = 2 * S1;

  const int T0 = blockIdx.x * nsb;          // first 32-row A-subtile
  int ns = TS - T0; if (ns > nsb) ns = nsb;
  if (ns <= 0) return;

  for (int i = t; i < MAXS; i += 512) sums[i] = 0.f;

  // Staging map: row = t>>4 (0..31), 16 lanes/row; load j covers float4 at
  // col j*64 + (t&15)*4 -> every load instruction fully coalesced (16B/lane).
  const int srow = t >> 4;
  const int sc = (t & 15) * 4;

  auto issue = [&](const float* __restrict__ base, int tau, float4* r) {
    const int gr = tau * 32 + srow;
    if (gr >= 0 && gr < N) {
      const float* s = base + (size_t)gr * 256 + sc;
      #pragma unroll
      for (int j = 0; j < 4; ++j)
        r[j] = *reinterpret_cast<const float4*>(s + j * 64);
    } else {
      #pragma unroll
      for (int j = 0; j < 4; ++j) r[j] = make_float4(0.f, 0.f, 0.f, 0.f);
    }
  };

  auto commit = [&](unsigned short* dst, float* ndst, int slot, const float4* r) {
    float nrm = 0.f;
    unsigned short* row = dst + slot * 32 * LDSH + srow * LDSH;
    #pragma unroll
    for (int j = 0; j < 4; ++j) {
      const float f0 = r[j].x, f1 = r[j].y, f2 = r[j].z, f3 = r[j].w;
      nrm = fmaf(f0, f0, nrm); nrm = fmaf(f1, f1, nrm);
      nrm = fmaf(f2, f2, nrm); nrm = fmaf(f3, f3, nrm);
      ushort4 h;
      h.x = __builtin_bit_cast(unsigned short, (__bf16)f0);
      h.y = __builtin_bit_cast(unsigned short, (__bf16)f1);
      h.z = __builtin_bit_cast(unsigned short, (__bf16)f2);
      h.w = __builtin_bit_cast(unsigned short, (__bf16)f3);
      *reinterpret_cast<ushort4*>(row + j * 64 + sc) = h;
    }
    nrm += __shfl_xor(nrm, 1); nrm += __shfl_xor(nrm, 2);
    nrm += __shfl_xor(nrm, 4); nrm += __shfl_xor(nrm, 8);
    if ((t & 15) == 0) ndst[slot * 32 + srow] = nrm;   // exact fp32 row norm
  };

  const int lane = t & 63;
  const int wid = t >> 6;        // 0..7; waves 0..4 compute
  const int l31 = lane & 31;
  const int hi = lane >> 5;

  // ---- Per-thread step slots (T-invariant): delta = arow - l31 - (wid-2)*32.
  int slotR[16];
  #pragma unroll
  for (int r = 0; r < 16; ++r) {
    int slot = -1;
    if (wid < 5) {
      const int arow = (r & 3) + 8 * (r >> 2) + 4 * hi;
      const int d = arow - l31 - (wid - 2) * 32;
      if (d >= 1) {
        const int k = d - 1;
        if (k < ms && (k % ss) == 0) slot = k / ss;
      } else if (d <= -2) {
        const int kk = -d - 1;
        if (kk <= ms && ((kk - 1) % ss) == 0) slot = S1 + (kk - 1) / ss;
      }
      if (slot >= MAXS) slot = -1;
    }
    slotR[r] = slot;
  }
  float racc[16];
  #pragma unroll
  for (int r = 0; r < 16; ++r) racc[r] = 0.f;

  // ---- Prologue: stage P tiles T0-2..T0+2 (2-deep pipe) + Q tile T0;
  //      leave (Q T0+1, P T0+3) in flight.
  float4 qA[4], pA[4], qB[4], pB[4];
  {
    float4 u[4], v[4];
    issue(P, T0 - 2, u);
    #pragma unroll
    for (int i = 0; i < 5; ++i) {
      if (i < 4) issue(P, T0 - 1 + i, v);
      commit(Bsh, NpS, (T0 - 2 + i + 12) % RING, u);
      #pragma unroll
      for (int j = 0; j < 4; ++j) u[j] = v[j];
    }
    issue(Q, T0, u);
    commit(Qsh, NqS, T0 & 1, u);
    issue(Q, T0 + 1, qA);
    issue(P, T0 + 3, pA);
  }
  __syncthreads();

  // ---- Main loop: issue 2-ahead, compute T, commit 1-ahead, one barrier.
  #pragma unroll 1
  for (int s = 0; s < ns; ++s) {
    const int T = T0 + s;
    issue(Q, T + 2, qB);
    issue(P, T + 4, pB);

    if (wid < 5) {
      const int tauW = T - 2 + wid;
      const int slot6 = (tauW + 12) % RING;
      const unsigned short* Ab = &Qsh[(T & 1) * 32 * LDSH + l31 * LDSH + hi * 8];
      const unsigned short* Bb = &Bsh[slot6 * 32 * LDSH + l31 * LDSH + hi * 8];
      f32x16 acc0 = {}, acc1 = {};
      #pragma unroll
      for (int ks = 0; ks < 16; ks += 2) {
        const bf16x8 a0 = *reinterpret_cast<const bf16x8*>(Ab + ks * 16);
        const bf16x8 b0 = *reinterpret_cast<const bf16x8*>(Bb + ks * 16);
        const bf16x8 a1 = *reinterpret_cast<const bf16x8*>(Ab + ks * 16 + 16);
        const bf16x8 b1 = *reinterpret_cast<const bf16x8*>(Bb + ks * 16 + 16);
        acc0 = __builtin_amdgcn_mfma_f32_32x32x16_bf16(a0, b0, acc0, 0, 0, 0);
        acc1 = __builtin_amdgcn_mfma_f32_32x32x16_bf16(a1, b1, acc1, 0, 0, 0);
      }

      const int bcol = tauW * 32 + l31;
      if (bcol >= 0 && bcol < N) {
        const float npW = NpS[slot6 * 32 + l31];
        const int aT = T * 32;
        #pragma unroll
        for (int r = 0; r < 16; ++r) {
          const int arow = (r & 3) + 8 * (r >> 2) + 4 * hi;
          if (slotR[r] >= 0 && (aT + arow) < N) {
            const float n2 = NqS[(T & 1) * 32 + arow] + npW
                             - 2.0f * (acc0[r] + acc1[r]);
            racc[r] += sqrtf(fmaxf(n2, 0.f));
          }
        }
      }
    }

    commit(Qsh, NqS, (T + 1) & 1, qA);
    commit(Bsh, NpS, (T + 3 + 12) % RING, pA);
    #pragma unroll
    for (int j = 0; j < 4; ++j) { qA[j] = qB[j]; pA[j] = pB[j]; }
    __syncthreads();
  }

  // ---- Once-per-block reduction: registers -> LDS slots -> global replicas.
  #pragma unroll
  for (int r = 0; r < 16; ++r)
    if (slotR[r] >= 0 && racc[r] != 0.f) atomicAdd(&sums[slotR[r]], racc[r]);
  __syncthreads();

  if (t < S && t < MAXS) {
    const float v = sums[t];
    if (v != 0.f)
      unsafeAtomicAdd(&ws[(size_t)(blockIdx.x & (NREP - 1)) * MAXS + t], (double)v);
  }
}

// One wrapped pair per step, exact fp32 like the reference.
__global__ void corner_kernel(const float* __restrict__ Q, const float* __restrict__ P,
                              double* __restrict__ ws,
                              const int* __restrict__ msp, const int* __restrict__ ssp,
                              int N) {
  const int ms = msp[0], ss = ssp[0];
  const int S1 = (ms + ss - 1) / ss;
  const int S = 2 * S1;
  const int s = blockIdx.x;
  if (s >= S) return;
  int k, qr, pr;
  if (s < S1) { k = s * ss;            qr = 0;           pr = N - (k + 1); }
  else        { k = 1 + (s - S1) * ss; qr = N - (k + 1); pr = 0; }
  const int t = threadIdx.x;   // 256 threads, one dim each
  const float e = Q[(size_t)qr * 256 + t] - P[(size_t)pr * 256 + t];
  float sq = e * e;
  #pragma unroll
  for (int off = 32; off >= 1; off >>= 1) sq += __shfl_down(sq, off);
  __shared__ float red[4];
  if ((t & 63) == 0) red[t >> 6] = sq;
  __syncthreads();
  if (t == 0)
    ws[(size_t)NREP * MAXS + s] = (double)sqrtf(red[0] + red[1] + red[2] + red[3]);
}

__global__ void finalize_kernel(const double* __restrict__ ws, float* __restrict__ out,
                                const int* __restrict__ msp, const int* __restrict__ ssp,
                                int N) {
  __shared__ double dist_sh[MAXS];
  const int t = threadIdx.x;
  const int ms = msp[0], ss = ssp[0];
  const int S1 = (ms + ss - 1) / ss;
  const int S = 2 * S1;
  if (t < S && t < MAXS) {
    double tot = 0.0;
    for (int rep = 0; rep < NREP; ++rep) tot += ws[(size_t)rep * MAXS + t];
    tot += ws[(size_t)NREP * MAXS + t];   // corner pair
    const int k = (t < S1) ? t * ss : 1 + (t - S1) * ss;
    dist_sh[t] = tot / (double)(N - k);
  }
  __syncthreads();
  if (t == 0) {
    int best = 0;
    double bd = dist_sh[0];
    for (int s = 1; s < S && s < MAXS; ++s)
      if (dist_sh[s] < bd) { bd = dist_sh[s]; best = s; }
    const int k = (best < S1) ? best * ss : 1 + (best - S1) * ss;
    out[0] = (best < S1) ? (float)k : -(float)k;
    out[1] = (float)bd;
  }
}

extern "C" void kernel_launch(void* const* d_in, const int* in_sizes, int n_in,
                              void* d_out, int out_size, void* d_ws, size_t ws_size,
                              hipStream_t stream) {
  const float* Q   = (const float*)d_in[0];
  const float* P   = (const float*)d_in[1];
  const int*   msp = (const int*)d_in[2];
  const int*   ssp = (const int*)d_in[3];
  const int N = in_sizes[0] / 256;
  double* ws = (double*)d_ws;

  hipMemsetAsync(d_ws, 0, (size_t)(NREP + 1) * MAXS * sizeof(double), stream);

  const int TS = (N + 31) / 32;                 // total 32-row A-subtiles
  int nsb = (TS + 249) / 250;                   // subtiles per block (~13)
  if (nsb < 1) nsb = 1;
  const int grid = (TS + nsb - 1) / nsb;        // ~241 blocks, 1/CU

  band_kernel<<<grid, 512, 0, stream>>>(Q, P, ws, msp, ssp, N, TS, nsb);
  corner_kernel<<<MAXS, 256, 0, stream>>>(Q, P, ws, msp, ssp, N);
  finalize_kernel<<<1, 128, 0, stream>>>(ws, (float*)d_out, msp, ssp, N);
}

// Round 6
// 72.469 us; speedup vs baseline: 1.0255x; 1.0255x over previous
//
#include <hip/hip_runtime.h>
#include <math.h>

// XYSearcher, sliding-window banded-GEMM, 32x32x16 MFMA, pipelined barriers.
//   ||q_a - p_b||^2 = ||q_a||^2 + ||p_b||^2 - 2 q_a.p_b
// Integer steps: step k pairs rows at delta = a-b = +(k+1) [pos] or -(k+1)
// [neg]; one wrapped corner pair per step (corner_kernel, exact fp32).
// Dots in bf16 MFMA, norms exact fp32 (absmax 0, rounds 3-5).
// Round-6 changes: main-loop barrier = lgkmcnt(0)+s_barrier ONLY (global
// loads ride across the barrier; __syncthreads would vmcnt(0)-drain them);
// 2-phase unrolled loop with two named register sets (no copies -> counted
// auto-waitcnt at commit); 3-deep rotated prologue.
// Ring-slot safety per iteration: compute(T) reads P slots (T+10..T+14)%6,
// commit writes (T+15)%6 == (T+3)%6 -- disjoint; Q write (T+1)&1 vs read T&1.

typedef __attribute__((ext_vector_type(8))) __bf16 bf16x8;
typedef __attribute__((ext_vector_type(16))) float f32x16;

#define LDSH 280     // shorts per LDS row (560 B = 35 x 16B slots, conflict-free)
#define RING 6       // P ring: 5-tile window + 1 incoming
#define MAXS 128
#define NREP 32

__global__ __launch_bounds__(512, 1)
void band_kernel(const float* __restrict__ Q, const float* __restrict__ P,
                 double* __restrict__ ws,
                 const int* __restrict__ msp, const int* __restrict__ ssp,
                 int N, int TS, int nsb) {
  __shared__ __align__(16) unsigned short Bsh[RING * 32 * LDSH];  // 105 KB
  __shared__ __align__(16) unsigned short Qsh[2 * 32 * LDSH];     // 35 KB
  __shared__ float NpS[RING * 32];
  __shared__ float NqS[2 * 32];
  __shared__ float sums[MAXS];

  const int t = threadIdx.x;
  const int ms = msp[0], ss = ssp[0];
  const int S1 = (ms + ss - 1) / ss;
  const int S = 2 * S1;

  const int T0 = blockIdx.x * nsb;          // first 32-row A-subtile
  int ns = TS - T0; if (ns > nsb) ns = nsb;
  if (ns <= 0) return;

  for (int i = t; i < MAXS; i += 512) sums[i] = 0.f;

  // Staging map: row = t>>4 (0..31), 16 lanes/row; load j covers float4 at
  // col j*64 + (t&15)*4 -> every load instruction fully coalesced.
  const int srow = t >> 4;
  const int sc = (t & 15) * 4;

  auto issue = [&](const float* __restrict__ base, int tau, float4* r) {
    const int gr = tau * 32 + srow;
    if (gr >= 0 && gr < N) {
      const float* s = base + (size_t)gr * 256 + sc;
      #pragma unroll
      for (int j = 0; j < 4; ++j)
        r[j] = *reinterpret_cast<const float4*>(s + j * 64);
    } else {
      #pragma unroll
      for (int j = 0; j < 4; ++j) r[j] = make_float4(0.f, 0.f, 0.f, 0.f);
    }
  };

  auto commit = [&](unsigned short* dst, float* ndst, int slot, const float4* r) {
    float nrm = 0.f;
    unsigned short* row = dst + slot * 32 * LDSH + srow * LDSH;
    #pragma unroll
    for (int j = 0; j < 4; ++j) {
      const float f0 = r[j].x, f1 = r[j].y, f2 = r[j].z, f3 = r[j].w;
      nrm = fmaf(f0, f0, nrm); nrm = fmaf(f1, f1, nrm);
      nrm = fmaf(f2, f2, nrm); nrm = fmaf(f3, f3, nrm);
      ushort4 h;
      h.x = __builtin_bit_cast(unsigned short, (__bf16)f0);
      h.y = __builtin_bit_cast(unsigned short, (__bf16)f1);
      h.z = __builtin_bit_cast(unsigned short, (__bf16)f2);
      h.w = __builtin_bit_cast(unsigned short, (__bf16)f3);
      *reinterpret_cast<ushort4*>(row + j * 64 + sc) = h;
    }
    nrm += __shfl_xor(nrm, 1); nrm += __shfl_xor(nrm, 2);
    nrm += __shfl_xor(nrm, 4); nrm += __shfl_xor(nrm, 8);
    if ((t & 15) == 0) ndst[slot * 32 + srow] = nrm;   // exact fp32 row norm
  };

  const int lane = t & 63;
  const int wid = t >> 6;        // 0..7; waves 0..4 compute
  const int l31 = lane & 31;
  const int hi = lane >> 5;

  // ---- Per-thread step slots (T-invariant): delta = arow - l31 - (wid-2)*32.
  int slotR[16];
  #pragma unroll
  for (int r = 0; r < 16; ++r) {
    int slot = -1;
    if (wid < 5) {
      const int arow = (r & 3) + 8 * (r >> 2) + 4 * hi;
      const int d = arow - l31 - (wid - 2) * 32;
      if (d >= 1) {
        const int k = d - 1;
        if (k < ms && (k % ss) == 0) slot = k / ss;
      } else if (d <= -2) {
        const int kk = -d - 1;
        if (kk <= ms && ((kk - 1) % ss) == 0) slot = S1 + (kk - 1) / ss;
      }
      if (slot >= MAXS) slot = -1;
    }
    slotR[r] = slot;
  }
  float racc[16];
  #pragma unroll
  for (int r = 0; r < 16; ++r) racc[r] = 0.f;

  auto do_compute = [&](int T) {
    const int tauW = T - 2 + wid;
    const int slot6 = (tauW + 12) % RING;
    const unsigned short* Ab = &Qsh[(T & 1) * 32 * LDSH + l31 * LDSH + hi * 8];
    const unsigned short* Bb = &Bsh[slot6 * 32 * LDSH + l31 * LDSH + hi * 8];
    f32x16 acc0 = {}, acc1 = {};
    #pragma unroll
    for (int ks = 0; ks < 16; ks += 2) {
      const bf16x8 a0 = *reinterpret_cast<const bf16x8*>(Ab + ks * 16);
      const bf16x8 b0 = *reinterpret_cast<const bf16x8*>(Bb + ks * 16);
      const bf16x8 a1 = *reinterpret_cast<const bf16x8*>(Ab + ks * 16 + 16);
      const bf16x8 b1 = *reinterpret_cast<const bf16x8*>(Bb + ks * 16 + 16);
      acc0 = __builtin_amdgcn_mfma_f32_32x32x16_bf16(a0, b0, acc0, 0, 0, 0);
      acc1 = __builtin_amdgcn_mfma_f32_32x32x16_bf16(a1, b1, acc1, 0, 0, 0);
    }
    const int bcol = tauW * 32 + l31;
    if (bcol >= 0 && bcol < N) {
      const float npW = NpS[slot6 * 32 + l31];
      const int aT = T * 32;
      #pragma unroll
      for (int r = 0; r < 16; ++r) {
        const int arow = (r & 3) + 8 * (r >> 2) + 4 * hi;
        if (slotR[r] >= 0 && (aT + arow) < N) {
          const float n2 = NqS[(T & 1) * 32 + arow] + npW
                           - 2.0f * (acc0[r] + acc1[r]);
          racc[r] += sqrtf(fmaxf(n2, 0.f));
        }
      }
    }
  };

  // ---- Prologue: stage P(T0-2..T0+2) + Q(T0) with 3-deep rotation; leave
  //      pending set A = (Q(T0+1), P(T0+3)) in flight for the main loop.
  float4 Aq[4], Ap[4], Bq[4], Bp[4];
  {
    float4 w0[4], w1[4], w2[4];
    issue(P, T0 - 2, w0);
    issue(P, T0 - 1, w1);
    issue(P, T0,     w2);
    commit(Bsh, NpS, (T0 + 10) % RING, w0);  issue(P, T0 + 1, w0);
    commit(Bsh, NpS, (T0 + 11) % RING, w1);  issue(P, T0 + 2, w1);
    commit(Bsh, NpS, (T0 + 12) % RING, w2);  issue(Q, T0,     w2);
    commit(Bsh, NpS, (T0 + 13) % RING, w0);
    commit(Bsh, NpS, (T0 + 14) % RING, w1);
    commit(Qsh, NqS, T0 & 1,           w2);
    issue(Q, T0 + 1, Aq);
    issue(P, T0 + 3, Ap);
  }
  __syncthreads();

  // ---- Main loop, 2-phase unrolled. Per STEP: issue 2-ahead into ISS set,
  //      compute T, commit COM set (tiles T+1 / T+3, issued last step),
  //      then lgkm-only barrier (global loads ride across).
#define STEP(TT, ISSq, ISSp, COMq, COMp)                                      \
  {                                                                           \
    const int T_ = (TT);                                                      \
    issue(Q, T_ + 2, ISSq);                                                   \
    issue(P, T_ + 4, ISSp);                                                   \
    if (wid < 5) do_compute(T_);                                              \
    commit(Qsh, NqS, (T_ + 1) & 1, COMq);                                     \
    commit(Bsh, NpS, (T_ + 15) % RING, COMp);                                 \
    __builtin_amdgcn_sched_barrier(0);                                        \
    asm volatile("s_waitcnt lgkmcnt(0)" ::: "memory");                        \
    __builtin_amdgcn_s_barrier();                                             \
    __builtin_amdgcn_sched_barrier(0);                                        \
  }

  int s = 0;
  for (; s + 2 <= ns; s += 2) {
    STEP(T0 + s,     Bq, Bp, Aq, Ap);
    STEP(T0 + s + 1, Aq, Ap, Bq, Bp);
  }
  if (s < ns) STEP(T0 + s, Bq, Bp, Aq, Ap);
#undef STEP

  // ---- Once-per-block reduction: registers -> LDS slots -> global replicas.
  #pragma unroll
  for (int r = 0; r < 16; ++r)
    if (slotR[r] >= 0 && racc[r] != 0.f) atomicAdd(&sums[slotR[r]], racc[r]);
  __syncthreads();

  if (t < S && t < MAXS) {
    const float v = sums[t];
    if (v != 0.f)
      unsafeAtomicAdd(&ws[(size_t)(blockIdx.x & (NREP - 1)) * MAXS + t], (double)v);
  }
}

// One wrapped pair per step, exact fp32 like the reference.
__global__ void corner_kernel(const float* __restrict__ Q, const float* __restrict__ P,
                              double* __restrict__ ws,
                              const int* __restrict__ msp, const int* __restrict__ ssp,
                              int N) {
  const int ms = msp[0], ss = ssp[0];
  const int S1 = (ms + ss - 1) / ss;
  const int S = 2 * S1;
  const int s = blockIdx.x;
  if (s >= S) return;
  int k, qr, pr;
  if (s < S1) { k = s * ss;            qr = 0;           pr = N - (k + 1); }
  else        { k = 1 + (s - S1) * ss; qr = N - (k + 1); pr = 0; }
  const int t = threadIdx.x;   // 256 threads, one dim each
  const float e = Q[(size_t)qr * 256 + t] - P[(size_t)pr * 256 + t];
  float sq = e * e;
  #pragma unroll
  for (int off = 32; off >= 1; off >>= 1) sq += __shfl_down(sq, off);
  __shared__ float red[4];
  if ((t & 63) == 0) red[t >> 6] = sq;
  __syncthreads();
  if (t == 0)
    ws[(size_t)NREP * MAXS + s] = (double)sqrtf(red[0] + red[1] + red[2] + red[3]);
}

__global__ void finalize_kernel(const double* __restrict__ ws, float* __restrict__ out,
                                const int* __restrict__ msp, const int* __restrict__ ssp,
                                int N) {
  __shared__ double dist_sh[MAXS];
  const int t = threadIdx.x;
  const int ms = msp[0], ss = ssp[0];
  const int S1 = (ms + ss - 1) / ss;
  const int S = 2 * S1;
  if (t < S && t < MAXS) {
    double tot = 0.0;
    for (int rep = 0; rep < NREP; ++rep) tot += ws[(size_t)rep * MAXS + t];
    tot += ws[(size_t)NREP * MAXS + t];   // corner pair
    const int k = (t < S1) ? t * ss : 1 + (t - S1) * ss;
    dist_sh[t] = tot / (double)(N - k);
  }
  __syncthreads();
  if (t == 0) {
    int best = 0;
    double bd = dist_sh[0];
    for (int s = 1; s < S && s < MAXS; ++s)
      if (dist_sh[s] < bd) { bd = dist_sh[s]; best = s; }
    const int k = (best < S1) ? best * ss : 1 + (best - S1) * ss;
    out[0] = (best < S1) ? (float)k : -(float)k;
    out[1] = (float)bd;
  }
}

extern "C" void kernel_launch(void* const* d_in, const int* in_sizes, int n_in,
                              void* d_out, int out_size, void* d_ws, size_t ws_size,
                              hipStream_t stream) {
  const float* Q   = (const float*)d_in[0];
  const float* P   = (const float*)d_in[1];
  const int*   msp = (const int*)d_in[2];
  const int*   ssp = (const int*)d_in[3];
  const int N = in_sizes[0] / 256;
  double* ws = (double*)d_ws;

  hipMemsetAsync(d_ws, 0, (size_t)(NREP + 1) * MAXS * sizeof(double), stream);

  const int TS = (N + 31) / 32;                 // total 32-row A-subtiles
  int nsb = (TS + 249) / 250;                   // subtiles per block (~13)
  if (nsb < 1) nsb = 1;
  const int grid = (TS + nsb - 1) / nsb;        // ~241 blocks, 1/CU

  band_kernel<<<grid, 512, 0, stream>>>(Q, P, ws, msp, ssp, N, TS, nsb);
  corner_kernel<<<MAXS, 256, 0, stream>>>(Q, P, ws, msp, ssp, N);
  finalize_kernel<<<1, 128, 0, stream>>>(ws, (float*)d_out, msp, ssp, N);
}

// Round 7
// 61.598 us; speedup vs baseline: 1.2064x; 1.1765x over previous
//
#include <hip/hip_runtime.h>
#include <math.h>

// XYSearcher, sliding-window banded-GEMM, 32x32x16 MFMA,
// PRODUCER/CONSUMER wave specialization (no per-iteration barrier).
//   ||q_a - p_b||^2 = ||q_a||^2 + ||p_b||^2 - 2 q_a.p_b
// Integer steps: step k pairs rows at delta = a-b = +(k+1) [pos] / -(k+1)
// [neg]; one wrapped corner pair per step (fused corner blocks, exact fp32).
// Dots in bf16 MFMA, norms exact fp32 (absmax 0, rounds 3-6).
// 9 waves: waves 0-4 consume (ds frag reads + MFMA + epilogue), waves 5-8
// produce (global loads + fp32 norms + bf16 cvt + LDS ring writes).
// Sync: packed per-wave progress counters in LDS, spin + s_sleep. Round r
// stages Q[T0+r] and P[T0+r+2]; consumer iter s needs rounds <= s
// (prod fields >= s+5 counting 4 prologue rounds); producer overwriting the
// ring slot of tile T0+r-4 (last read at iter r-2) needs cons fields >= r-1.

typedef __attribute__((ext_vector_type(8))) __bf16 bf16x8;
typedef __attribute__((ext_vector_type(16))) float f32x16;
typedef __attribute__((ext_vector_type(8))) unsigned short us8;

#define LDSH 280     // shorts per LDS row (560 B = 35 x 16B slots, conflict-free)
#define RING 6       // P ring slots
#define MAXS 128
#define NREP 32

__device__ __forceinline__ unsigned short f2bf(float x) {
  return __builtin_bit_cast(unsigned short, (__bf16)x);
}

__global__ __launch_bounds__(576, 1)
void band_kernel(const float* __restrict__ Q, const float* __restrict__ P,
                 double* __restrict__ ws,
                 const int* __restrict__ msp, const int* __restrict__ ssp,
                 int N, int TS, int nsb, int gridB) {
  __shared__ __align__(16) unsigned short Bsh[RING * 32 * LDSH];  // 105 KB
  __shared__ __align__(16) unsigned short Qsh[2 * 32 * LDSH];     // 35 KB
  __shared__ float NpS[RING * 32];
  __shared__ float NqS[2 * 32];
  __shared__ float sums[MAXS];
  __shared__ float red[12];
  __shared__ int packs[2];   // [0] prod (4 x 8-bit fields), [1] cons (5 x 6-bit)

  const int t = threadIdx.x;
  const int lane = t & 63;
  const int wid = t >> 6;          // 0..8
  const int ms = msp[0], ss = ssp[0];
  const int S1 = (ms + ss - 1) / ss;
  const int S = 2 * S1;

  // ---------------- fused corner blocks: one wrapped pair per step ---------
  if (blockIdx.x >= gridB) {
    const int si = blockIdx.x - gridB;
    if (si >= S) return;
    int k, qr, pr;
    if (si < S1) { k = si * ss;            qr = 0;           pr = N - (k + 1); }
    else         { k = 1 + (si - S1) * ss; qr = N - (k + 1); pr = 0; }
    float sq = 0.f;
    if (t < 256) {
      const float e = Q[(size_t)qr * 256 + t] - P[(size_t)pr * 256 + t];
      sq = e * e;
    }
    #pragma unroll
    for (int off = 32; off >= 1; off >>= 1) sq += __shfl_xor(sq, off);
    if (lane == 0) red[wid] = sq;
    __syncthreads();
    if (t == 0) {
      float tot = 0.f;
      #pragma unroll
      for (int w = 0; w < 9; ++w) tot += red[w];
      ws[(size_t)NREP * MAXS + si] = (double)sqrtf(tot);
    }
    return;
  }

  // ---------------- band blocks -------------------------------------------
  const int T0 = blockIdx.x * nsb;
  int ns = TS - T0; if (ns > nsb) ns = nsb;
  if (ns <= 0) return;

  for (int i = t; i < MAXS; i += 576) sums[i] = 0.f;
  if (t == 0) { packs[0] = 0; packs[1] = 0; }
  __syncthreads();

  volatile int* vprod = &packs[0];
  volatile int* vcons = &packs[1];

  if (wid >= 5) {
    // ================= PRODUCER waves (5..8) ==============================
    const int pw = wid - 5;              // 0..3: rows pw*8 .. pw*8+7 of each tile
    const int rr = pw * 8 + (lane >> 3); // tile-local row 0..31
    const int li = lane & 7;             // 8 lanes per row, 32 floats each

    float4 vp[8], vq[8];

    auto issueT = [&](const float* __restrict__ base, int tau, float4* v) {
      const int gr = tau * 32 + rr;
      if (gr >= 0 && gr < N) {
        const float* src = base + (size_t)gr * 256 + li * 8;
        #pragma unroll
        for (int j = 0; j < 4; ++j) {
          v[2 * j]     = *reinterpret_cast<const float4*>(src + j * 64);
          v[2 * j + 1] = *reinterpret_cast<const float4*>(src + j * 64 + 4);
        }
      } else {
        #pragma unroll
        for (int j = 0; j < 8; ++j) v[j] = make_float4(0.f, 0.f, 0.f, 0.f);
      }
    };

    auto commitT = [&](unsigned short* dst, float* ndst, int slot, const float4* v) {
      float nrm = 0.f;
      unsigned short* row = dst + slot * 32 * LDSH + rr * LDSH + li * 8;
      #pragma unroll
      for (int j = 0; j < 4; ++j) {
        const float f0 = v[2*j].x, f1 = v[2*j].y, f2 = v[2*j].z, f3 = v[2*j].w;
        const float f4 = v[2*j+1].x, f5 = v[2*j+1].y, f6 = v[2*j+1].z, f7 = v[2*j+1].w;
        nrm = fmaf(f0, f0, nrm); nrm = fmaf(f1, f1, nrm);
        nrm = fmaf(f2, f2, nrm); nrm = fmaf(f3, f3, nrm);
        nrm = fmaf(f4, f4, nrm); nrm = fmaf(f5, f5, nrm);
        nrm = fmaf(f6, f6, nrm); nrm = fmaf(f7, f7, nrm);
        us8 h;
        h[0] = f2bf(f0); h[1] = f2bf(f1); h[2] = f2bf(f2); h[3] = f2bf(f3);
        h[4] = f2bf(f4); h[5] = f2bf(f5); h[6] = f2bf(f6); h[7] = f2bf(f7);
        *reinterpret_cast<us8*>(row + j * 64) = h;
      }
      nrm += __shfl_xor(nrm, 1);
      nrm += __shfl_xor(nrm, 2);
      nrm += __shfl_xor(nrm, 4);
      if (li == 0) ndst[slot * 32 + rr] = nrm;   // exact fp32 row norm
    };

    #pragma unroll 1
    for (int r = -4; r < ns; ++r) {
      const int tauP = T0 + r + 2;
      const bool doQ = (r >= 0);
      issueT(P, tauP, vp);                  // loads in flight during the spin
      if (doQ) issueT(Q, T0 + r, vq);
      const int needc = r - 1;              // all consumers finished iter r-2
      if (needc > 0) {
        for (;;) {
          const int v = *vcons;
          if ((v & 63) >= needc && ((v >> 6) & 63) >= needc &&
              ((v >> 12) & 63) >= needc && ((v >> 18) & 63) >= needc &&
              ((v >> 24) & 63) >= needc) break;
          __builtin_amdgcn_s_sleep(2);
        }
      }
      commitT(Bsh, NpS, (tauP + 12) % RING, vp);
      if (doQ) commitT(Qsh, NqS, (T0 + r) & 1, vq);
      __threadfence_block();                // LDS writes visible before signal
      if (lane == 0) atomicAdd(&packs[0], 1 << (8 * pw));
    }
  } else {
    // ================= CONSUMER waves (0..4) ==============================
    const int l31 = lane & 31;
    const int hi = lane >> 5;

    // Per-thread step slots (T-invariant): delta = arow - l31 - (wid-2)*32.
    int slotR[16];
    #pragma unroll
    for (int r = 0; r < 16; ++r) {
      const int arow = (r & 3) + 8 * (r >> 2) + 4 * hi;
      const int d = arow - l31 - (wid - 2) * 32;
      int slot = -1;
      if (d >= 1) {
        const int k = d - 1;
        if (k < ms && (k % ss) == 0) slot = k / ss;
      } else if (d <= -2) {
        const int kk = -d - 1;
        if (kk <= ms && ((kk - 1) % ss) == 0) slot = S1 + (kk - 1) / ss;
      }
      if (slot >= MAXS) slot = -1;
      slotR[r] = slot;
    }
    float racc[16];
    #pragma unroll
    for (int r = 0; r < 16; ++r) racc[r] = 0.f;

    #pragma unroll 1
    for (int s = 0; s < ns; ++s) {
      const int T = T0 + s;
      const int need = s + 5;               // rounds -4..s complete
      for (;;) {
        const int v = *vprod;
        if ((v & 255) >= need && ((v >> 8) & 255) >= need &&
            ((v >> 16) & 255) >= need && ((v >> 24) & 255) >= need) break;
        __builtin_amdgcn_s_sleep(2);
      }
      __threadfence_block();

      const int tauW = T - 2 + wid;
      const int slot6 = (tauW + 12) % RING;
      const unsigned short* Ab = &Qsh[(T & 1) * 32 * LDSH + l31 * LDSH + hi * 8];
      const unsigned short* Bb = &Bsh[slot6 * 32 * LDSH + l31 * LDSH + hi * 8];
      f32x16 acc0 = {}, acc1 = {};
      __builtin_amdgcn_s_setprio(1);
      #pragma unroll
      for (int ks = 0; ks < 16; ks += 2) {
        const bf16x8 a0 = *reinterpret_cast<const bf16x8*>(Ab + ks * 16);
        const bf16x8 b0 = *reinterpret_cast<const bf16x8*>(Bb + ks * 16);
        const bf16x8 a1 = *reinterpret_cast<const bf16x8*>(Ab + ks * 16 + 16);
        const bf16x8 b1 = *reinterpret_cast<const bf16x8*>(Bb + ks * 16 + 16);
        acc0 = __builtin_amdgcn_mfma_f32_32x32x16_bf16(a0, b0, acc0, 0, 0, 0);
        acc1 = __builtin_amdgcn_mfma_f32_32x32x16_bf16(a1, b1, acc1, 0, 0, 0);
      }
      __builtin_amdgcn_s_setprio(0);

      const int bcol = tauW * 32 + l31;
      if (bcol >= 0 && bcol < N) {
        const float npW = NpS[slot6 * 32 + l31];
        const int aT = T * 32;
        #pragma unroll
        for (int r = 0; r < 16; ++r) {
          const int arow = (r & 3) + 8 * (r >> 2) + 4 * hi;
          if (slotR[r] >= 0 && (aT + arow) < N) {
            const float n2 = NqS[(T & 1) * 32 + arow] + npW
                             - 2.0f * (acc0[r] + acc1[r]);
            racc[r] += sqrtf(fmaxf(n2, 0.f));
          }
        }
      }

      __threadfence_block();                // frag reads retired before signal
      if (lane == 0) atomicAdd(&packs[1], 1 << (6 * wid));
    }

    // Once-per-block: registers -> LDS step slots.
    #pragma unroll
    for (int r = 0; r < 16; ++r)
      if (slotR[r] >= 0 && racc[r] != 0.f) atomicAdd(&sums[slotR[r]], racc[r]);
  }

  __syncthreads();
  if (t < S && t < MAXS) {
    const float v = sums[t];
    if (v != 0.f)
      unsafeAtomicAdd(&ws[(size_t)(blockIdx.x & (NREP - 1)) * MAXS + t], (double)v);
  }
}

__global__ void finalize_kernel(const double* __restrict__ ws, float* __restrict__ out,
                                const int* __restrict__ msp, const int* __restrict__ ssp,
                                int N) {
  __shared__ double dist_sh[MAXS];
  const int t = threadIdx.x;
  const int ms = msp[0], ss = ssp[0];
  const int S1 = (ms + ss - 1) / ss;
  const int S = 2 * S1;
  if (t < S && t < MAXS) {
    double tot = 0.0;
    for (int rep = 0; rep < NREP; ++rep) tot += ws[(size_t)rep * MAXS + t];
    tot += ws[(size_t)NREP * MAXS + t];   // corner pair
    const int k = (t < S1) ? t * ss : 1 + (t - S1) * ss;
    dist_sh[t] = tot / (double)(N - k);
  }
  __syncthreads();
  if (t == 0) {
    int best = 0;
    double bd = dist_sh[0];
    for (int s = 1; s < S && s < MAXS; ++s)
      if (dist_sh[s] < bd) { bd = dist_sh[s]; best = s; }
    const int k = (best < S1) ? best * ss : 1 + (best - S1) * ss;
    out[0] = (best < S1) ? (float)k : -(float)k;
    out[1] = (float)bd;
  }
}

extern "C" void kernel_launch(void* const* d_in, const int* in_sizes, int n_in,
                              void* d_out, int out_size, void* d_ws, size_t ws_size,
                              hipStream_t stream) {
  const float* Q   = (const float*)d_in[0];
  const float* P   = (const float*)d_in[1];
  const int*   msp = (const int*)d_in[2];
  const int*   ssp = (const int*)d_in[3];
  const int N = in_sizes[0] / 256;
  double* ws = (double*)d_ws;

  hipMemsetAsync(d_ws, 0, (size_t)(NREP + 1) * MAXS * sizeof(double), stream);

  const int TS = (N + 31) / 32;                 // total 32-row A-subtiles
  int nsb = (TS + 249) / 250;                   // subtiles per block (~13)
  if (nsb < 1) nsb = 1;
  if (nsb > 60) nsb = 60;                       // packed 6-bit counters cap
  const int gridB = (TS + nsb - 1) / nsb;       // ~241 band blocks, 1/CU

  band_kernel<<<gridB + MAXS, 576, 0, stream>>>(Q, P, ws, msp, ssp,
                                                N, TS, nsb, gridB);
  finalize_kernel<<<1, 128, 0, stream>>>(ws, (float*)d_out, msp, ssp, N);
}